// Round 8
// baseline (218.941 us; speedup 1.0000x reference)
//
#include <hip/hip_runtime.h>
#include <hip/hip_bf16.h>

namespace {

constexpr int MM = 64;
constexpr int KK = 4096;
constexpr int NN = 11008;
constexpr int NZROW = NN / 8;      // 1376
constexpr int BN = 128;            // cols per block tile
constexpr int KSPLIT = 8;
constexpr int KSEG = KK / KSPLIT;  // 512
constexpr int NTILES = NN / BN;    // 86
constexpr int SCK = 128;           // superchunk k-extent == quant group
constexpr int NSC = KSEG / SCK;    // 4 superchunks per block
constexpr int AROW = 68;           // A LDS row stride in ints (64 data + 4 pad)
constexpr int ABUF = MM * AROW;    // 4352 ints per buffer
constexpr size_t CNT_OFF = (size_t)KSPLIT * MM * NN;            // float offset of counters
constexpr size_t WS_NEED = CNT_OFF * 4 + NTILES * 4;            // partials + counters

typedef float f32x4 __attribute__((ext_vector_type(4)));
typedef short s16x8 __attribute__((ext_vector_type(8)));
typedef int   i32x4 __attribute__((ext_vector_type(4)));

// truncating bf16 pack of (even,odd) -> one dword, 1 instr
__device__ __forceinline__ int perm_trunc(float even, float odd) {
  return (int)__builtin_amdgcn_perm(__float_as_uint(odd), __float_as_uint(even), 0x07060302u);
}
// RNE bf16 pack
__device__ __forceinline__ unsigned rne_adj(float f) {
  unsigned u = __float_as_uint(f);
  return u + 0x7FFFu + ((u >> 16) & 1u);
}
__device__ __forceinline__ int pack_rne(float even, float odd) {
  return (int)__builtin_amdgcn_perm(rne_adj(odd), rne_adj(even), 0x07060302u);
}

// fallback path only: out[m][n] = bias[n], atomics on top
__global__ __launch_bounds__(256) void prep_kernel(
    const float* __restrict__ bias, float* __restrict__ out)
{
  const int i = blockIdx.x * 256 + threadIdx.x;
  out[i] = bias[i % NN];
}

// R8: R7 structure (B dequant fully in registers, A in LDS, 4 barriers)
// + depth-2-SC qw prefetch + fused split-k reduction (per-ntile semaphore;
// last-arriving block reduces all 8 partials + bias and writes out).
template<bool ATOMIC>
__global__ __launch_bounds__(256, 3) void gptq_gemm_kernel(
    const float* __restrict__ x, const int* __restrict__ qw,
    const int* __restrict__ qz, const float* __restrict__ scales,
    const float* __restrict__ bias, float* __restrict__ ws,
    int* __restrict__ cnt, float* __restrict__ out)
{
  __shared__ int Albuf[2 * ABUF];   // 34.8 KB
  __shared__ int last_flag;

  const int tid  = threadIdx.x;
  const int wave = tid >> 6;
  const int lane = tid & 63;
  const int c    = lane & 15;
  const int quad = lane >> 4;

  const int ks    = blockIdx.x & 7;
  const int ntile = blockIdx.x >> 3;
  const int n0    = ntile * BN;
  const int kbase = ks * KSEG;

  // A staging coords
  const int sm  = tid >> 2;
  const int skq = tid & 3;
  const float* xs = x + sm * KK + kbase + skq * 32;

  // B coords: wave owns n-slice [n0+wave*32, +32)
  const int nb0   = n0 + wave * 32;
  const int ncol0 = nb0 + c;
  const int ncol1 = nb0 + 16 + c;
  const int* qwl  = qw + (size_t)quad * NN + ncol0;
  const int g0    = ks * NSC;

  f32x4 acc[8];
  #pragma unroll
  for (int i = 0; i < 8; ++i) acc[i] = {0.f, 0.f, 0.f, 0.f};

  f32x4 xv[8];
  int   qv[2][4][2];   // depth-2 superchunk qw prefetch
  float ps0[2], ps1[2];
  int   pz0[2], pz1[2];

  auto stage = [&](int sl) {
    int* Ab = Albuf + sl * ABUF;
    int iw[16];
    #pragma unroll
    for (int j = 0; j < 8; ++j) {
      iw[2 * j]     = pack_rne(xv[j].x, xv[j].y);
      iw[2 * j + 1] = pack_rne(xv[j].z, xv[j].w);
    }
    #pragma unroll
    for (int gq = 0; gq < 4; ++gq)
      *(i32x4*)&Ab[sm * AROW + skq * 16 + gq * 4] = *(const i32x4*)&iw[gq * 4];
  };
  auto pfQ = [&](int s) {   // load all 8 qw dwords of superchunk s into slot s&1
    #pragma unroll
    for (int ch = 0; ch < 4; ++ch) {
      const size_t ro = (size_t)(ks * 64 + s * 16 + ch * 4) * NN;
      qv[s & 1][ch][0] = qwl[ro];
      qv[s & 1][ch][1] = qwl[ro + 16];
    }
  };

  // ---- prologue ----
  pfQ(0); pfQ(1);
  #pragma unroll
  for (int j = 0; j < 8; ++j) xv[j] = *(const f32x4*)(xs + j * 4);
  ps0[0] = scales[(size_t)g0 * NN + ncol0];
  ps1[0] = scales[(size_t)g0 * NN + ncol1];
  pz0[0] = qz[(size_t)g0 * NZROW + (ncol0 >> 3)];
  pz1[0] = qz[(size_t)g0 * NZROW + (ncol1 >> 3)];
  stage(0);
  __asm__ volatile("s_waitcnt lgkmcnt(0)\n\ts_barrier" ::: "memory");

  #pragma unroll
  for (int s = 0; s < NSC; ++s) {
    const int sl = s & 1;
    if (s + 1 < NSC) {
      #pragma unroll
      for (int j = 0; j < 8; ++j) xv[j] = *(const f32x4*)(xs + (s + 1) * SCK + j * 4);
      const int g1 = g0 + s + 1;
      ps0[(s + 1) & 1] = scales[(size_t)g1 * NN + ncol0];
      ps1[(s + 1) & 1] = scales[(size_t)g1 * NN + ncol1];
      pz0[(s + 1) & 1] = qz[(size_t)g1 * NZROW + (ncol0 >> 3)];
      pz1[(s + 1) & 1] = qz[(size_t)g1 * NZROW + (ncol1 >> 3)];
    }
    const float s0v = ps0[sl], s1v = ps1[sl];
    const float C0 = (float)(0x800000 + ((pz0[sl] >> ((ncol0 & 7) * 4)) & 15) + 1);
    const float C1 = (float)(0x800000 + ((pz1[sl] >> ((ncol1 & 7) * 4)) & 15) + 1);
    const int* Ab = Albuf + sl * ABUF;

    #pragma unroll
    for (int ch = 0; ch < 4; ++ch) {
      const int v0 = qv[sl][ch][0], v1 = qv[sl][ch][1];
      if (s + 2 < NSC) {   // refill slot for SC s+2 (same slot parity)
        const size_t ro = (size_t)(ks * 64 + (s + 2) * 16 + ch * 4) * NN;
        qv[sl][ch][0] = qwl[ro];
        qv[sl][ch][1] = qwl[ro + 16];
      }
      // exact dequant: qf=(nib|0x4B000000)=2^23+q; d=qf-C (Sterbenz, int
      // q-z-1); w=s*d; truncating bf16 pack
      i32x4 b0, b1;
      {
        const float w0 = s0v * (__int_as_float(((v0      ) & 15) | 0x4B000000) - C0);
        const float w1 = s0v * (__int_as_float(((v0 >>  4) & 15) | 0x4B000000) - C0);
        const float w2 = s0v * (__int_as_float(((v0 >>  8) & 15) | 0x4B000000) - C0);
        const float w3 = s0v * (__int_as_float(((v0 >> 12) & 15) | 0x4B000000) - C0);
        const float w4 = s0v * (__int_as_float(((v0 >> 16) & 15) | 0x4B000000) - C0);
        const float w5 = s0v * (__int_as_float(((v0 >> 20) & 15) | 0x4B000000) - C0);
        const float w6 = s0v * (__int_as_float(((v0 >> 24) & 15) | 0x4B000000) - C0);
        const float w7 = s0v * (__int_as_float(((v0 >> 28) & 15) | 0x4B000000) - C0);
        b0.x = perm_trunc(w0, w1); b0.y = perm_trunc(w2, w3);
        b0.z = perm_trunc(w4, w5); b0.w = perm_trunc(w6, w7);
      }
      {
        const float w0 = s1v * (__int_as_float(((v1      ) & 15) | 0x4B000000) - C1);
        const float w1 = s1v * (__int_as_float(((v1 >>  4) & 15) | 0x4B000000) - C1);
        const float w2 = s1v * (__int_as_float(((v1 >>  8) & 15) | 0x4B000000) - C1);
        const float w3 = s1v * (__int_as_float(((v1 >> 12) & 15) | 0x4B000000) - C1);
        const float w4 = s1v * (__int_as_float(((v1 >> 16) & 15) | 0x4B000000) - C1);
        const float w5 = s1v * (__int_as_float(((v1 >> 20) & 15) | 0x4B000000) - C1);
        const float w6 = s1v * (__int_as_float(((v1 >> 24) & 15) | 0x4B000000) - C1);
        const float w7 = s1v * (__int_as_float(((v1 >> 28) & 15) | 0x4B000000) - C1);
        b1.x = perm_trunc(w0, w1); b1.y = perm_trunc(w2, w3);
        b1.z = perm_trunc(w4, w5); b1.w = perm_trunc(w6, w7);
      }
      const s16x8 bf0 = __builtin_bit_cast(s16x8, b0);
      const s16x8 bf1 = __builtin_bit_cast(s16x8, b1);

      #pragma unroll
      for (int t = 0; t < 4; ++t) {
        const s16x8 af = *(const s16x8*)&Ab[(16 * t + c) * AROW + ch * 16 + quad * 4];
        acc[2 * t]     = __builtin_amdgcn_mfma_f32_16x16x32_bf16(af, bf0, acc[2 * t],     0, 0, 0);
        acc[2 * t + 1] = __builtin_amdgcn_mfma_f32_16x16x32_bf16(af, bf1, acc[2 * t + 1], 0, 0, 0);
      }
    }

    if (s + 1 < NSC) {
      stage((s + 1) & 1);
      __asm__ volatile("s_waitcnt lgkmcnt(0)\n\ts_barrier" ::: "memory");
    }
  }

  // ---- epilogue ----
  if (ATOMIC) {
    #pragma unroll
    for (int t = 0; t < 4; ++t)
      #pragma unroll
      for (int u = 0; u < 2; ++u) {
        const int N = nb0 + u * 16 + c;
        const f32x4 a = acc[2 * t + u];
        const int m0 = 16 * t + quad * 4;
        atomicAdd(&out[(m0 + 0) * NN + N], a.x);
        atomicAdd(&out[(m0 + 1) * NN + N], a.y);
        atomicAdd(&out[(m0 + 2) * NN + N], a.z);
        atomicAdd(&out[(m0 + 3) * NN + N], a.w);
      }
  } else {
    // store partial
    float* wsp = ws + (size_t)ks * (MM * NN);
    #pragma unroll
    for (int t = 0; t < 4; ++t)
      #pragma unroll
      for (int u = 0; u < 2; ++u) {
        const int N = nb0 + u * 16 + c;
        const f32x4 a = acc[2 * t + u];
        const int m0 = 16 * t + quad * 4;
        wsp[(m0 + 0) * NN + N] = a.x;
        wsp[(m0 + 1) * NN + N] = a.y;
        wsp[(m0 + 2) * NN + N] = a.z;
        wsp[(m0 + 3) * NN + N] = a.w;
      }
    // split-k semaphore: last block per ntile reduces
    __threadfence();
    __syncthreads();
    if (tid == 0) {
      const int prev = __hip_atomic_fetch_add(&cnt[ntile], 1,
                          __ATOMIC_ACQ_REL, __HIP_MEMORY_SCOPE_AGENT);
      last_flag = (prev == KSPLIT - 1);
    }
    __syncthreads();
    if (last_flag) {
      // reduce 64x128 tile: 2048 f32x4, 8 per thread
      #pragma unroll
      for (int j = 0; j < 8; ++j) {
        const int idx = j * 256 + tid;        // 0..2047
        const int m   = idx >> 5;
        const int nc  = n0 + (idx & 31) * 4;
        const size_t o = (size_t)m * NN + nc;
        f32x4 sum = *(const f32x4*)(bias + nc);
        #pragma unroll
        for (int p = 0; p < KSPLIT; ++p)
          sum += *(const f32x4*)(ws + (size_t)p * (MM * NN) + o);
        *(f32x4*)(out + o) = sum;
      }
    }
  }
}

} // namespace

extern "C" void kernel_launch(void* const* d_in, const int* in_sizes, int n_in,
                              void* d_out, int out_size, void* d_ws, size_t ws_size,
                              hipStream_t stream) {
  const float* x      = (const float*)d_in[0];
  const int*   qw     = (const int*)d_in[1];
  const int*   qz     = (const int*)d_in[2];
  const float* scales = (const float*)d_in[3];
  const float* bias   = (const float*)d_in[4];
  float* out = (float*)d_out;

  if (ws_size >= WS_NEED) {
    float* ws  = (float*)d_ws;
    int*   cnt = (int*)(ws + CNT_OFF);
    hipMemsetAsync(cnt, 0, NTILES * sizeof(int), stream);   // graph-capturable
    gptq_gemm_kernel<false><<<NTILES * KSPLIT, 256, 0, stream>>>(
        x, qw, qz, scales, bias, ws, cnt, out);
  } else {
    prep_kernel<<<(MM * NN) / 256, 256, 0, stream>>>(bias, out);
    gptq_gemm_kernel<true><<<NTILES * KSPLIT, 256, 0, stream>>>(
        x, qw, qz, scales, bias, nullptr, nullptr, out);
  }
}

// Round 9
// 107.397 us; speedup vs baseline: 2.0386x; 2.0386x over previous
//
#include <hip/hip_runtime.h>
#include <hip/hip_bf16.h>

namespace {

constexpr int MM = 64;
constexpr int KK = 4096;
constexpr int NN = 11008;
constexpr int NZROW = NN / 8;       // 1376
constexpr int KSPLIT = 8;
constexpr int KSEG = KK / KSPLIT;   // 512
constexpr int NTILES = NN / 128;    // 86
constexpr int NCH = KSEG / 32;      // 16 k-chunks of 32
constexpr int BLK_FLOATS = 64 * 128;                       // 8192 partial floats per block
constexpr size_t XT8_OFF = (size_t)NTILES * KSPLIT * BLK_FLOATS;   // float offset of xT8
constexpr size_t WS_NEED = XT8_OFF * 4 + (size_t)KK * MM * 2;      // partials + xT8(bf16)

typedef float f32x4 __attribute__((ext_vector_type(4)));
typedef short s16x8 __attribute__((ext_vector_type(8)));
typedef int   i32x4 __attribute__((ext_vector_type(4)));

// truncating bf16 pack of (even,odd) -> one dword, 1 instr
__device__ __forceinline__ int perm_trunc(float even, float odd) {
  return (int)__builtin_amdgcn_perm(__float_as_uint(odd), __float_as_uint(even), 0x07060302u);
}
// RNE bf16 pack
__device__ __forceinline__ unsigned rne_adj(float f) {
  unsigned u = __float_as_uint(f);
  return u + 0x7FFFu + ((u >> 16) & 1u);
}
__device__ __forceinline__ int pack_rne(float even, float odd) {
  return (int)__builtin_amdgcn_perm(rne_adj(odd), rne_adj(even), 0x07060302u);
}

__device__ short g_xT8[KK * MM];   // 512 KB BSS — fallback if ws too small

// Build xT8[kblk][m][j] = bf16(x[m][kblk*8+j]) : one 16B unit per (kblk,m).
// B-fragments for the swapped-operand MFMA are then direct 16B loads.
__global__ __launch_bounds__(256) void xt8_kernel(
    const float* __restrict__ x, short* __restrict__ xT8)
{
  if (xT8 == nullptr) xT8 = g_xT8;
  const int m    = blockIdx.x >> 1;
  const int kblk = (blockIdx.x & 1) * 256 + threadIdx.x;
  const float* p = x + m * KK + kblk * 8;
  const f32x4 a = *(const f32x4*)p;
  const f32x4 b = *(const f32x4*)(p + 4);
  i32x4 w;
  w.x = pack_rne(a.x, a.y);
  w.y = pack_rne(a.z, a.w);
  w.z = pack_rne(b.x, b.y);
  w.w = pack_rne(b.z, b.w);
  *(i32x4*)(xT8 + ((size_t)kblk * MM + m) * 8) = w;
}

// fallback path only: out[m][n] = bias[n], atomics on top
__global__ __launch_bounds__(256) void prep_kernel(
    const float* __restrict__ bias, float* __restrict__ out)
{
  const int i = blockIdx.x * 256 + threadIdx.x;
  out[i] = bias[i % NN];
}

// un-permute + sum KSPLIT partials + bias
__global__ __launch_bounds__(256) void reduce_kernel(
    const float* __restrict__ ws, const float* __restrict__ bias,
    float* __restrict__ out)
{
  const int i4 = (blockIdx.x * 256 + threadIdx.x) * 4;
  const int m  = i4 / NN;
  const int n  = i4 - m * NN;
  const int ntile = n >> 7, nt = n & 127;
  const int wv = nt >> 5, ns = (nt >> 4) & 1, qd = (nt >> 2) & 3;
  const int mt = m >> 4,  ml = m & 15;
  const float* base = ws + (size_t)(ntile * 8) * BLK_FLOATS
                    + ((wv * 8 + ns * 4 + mt) * 64 + qd * 16 + ml) * 4;
  f32x4 sum = *(const f32x4*)(bias + n);
  #pragma unroll
  for (int p = 0; p < KSPLIT; ++p)
    sum += *(const f32x4*)(base + (size_t)p * BLK_FLOATS);
  *(f32x4*)(out + i4) = sum;
}

// R9: zero-LDS, zero-barrier gemm. Operands swapped: A = dequantized W
// (one qw dword == one A-fragment: A[row=lane&15 -> n][k=quad*8+j]),
// B = xT8 (16B coalesced frag loads, L2-resident). Waves fully independent;
// latency hidden by TLP (12 waves/CU) + depth-2-SC qw prefetch + depth-1
// B-frag prefetch. D tile: row=n_local=quad*4+reg, col=m=lane&15 (m89).
// Partials stored coalesced in permuted layout; reduce_kernel un-permutes.
template<bool ATOMIC>
__global__ __launch_bounds__(256, 3) void gptq_gemm_kernel(
    const int* __restrict__ qw, const int* __restrict__ qz,
    const float* __restrict__ scales, const short* __restrict__ xT8p,
    float* __restrict__ outws)
{
  const short* xT8 = (xT8p == nullptr) ? g_xT8 : xT8p;
  const int tid  = threadIdx.x;
  const int wave = tid >> 6;
  const int lane = tid & 63;
  const int ml   = lane & 15;
  const int quad = lane >> 4;          // 0..3

  const int ks    = blockIdx.x & 7;
  const int ntile = blockIdx.x >> 3;
  const int nw0   = ntile * 128 + wave * 32;
  const int ncol0 = nw0 + ml;
  const int rbase = ks * 64;           // qw dword-row base for this k-split

  const int* qwl = qw + (size_t)(rbase + quad) * NN + ncol0;

  // per-SC scale/zero constants, all loaded upfront (L2/L3-warm)
  const int g0 = ks * 4;
  float s0[4], s1[4], C0[4], C1[4];
  #pragma unroll
  for (int s = 0; s < 4; ++s) {
    s0[s] = scales[(size_t)(g0 + s) * NN + ncol0];
    s1[s] = scales[(size_t)(g0 + s) * NN + ncol0 + 16];
    const int z0 = (qz[(size_t)(g0 + s) * NZROW + ((ncol0)      >> 3)] >> ((ncol0 & 7) * 4)) & 15;
    const int z1 = (qz[(size_t)(g0 + s) * NZROW + ((ncol0 + 16) >> 3)] >> ((ncol0 & 7) * 4)) & 15;
    C0[s] = (float)(0x800000 + z0 + 1);
    C1[s] = (float)(0x800000 + z1 + 1);
  }

  // qw prefetch: per-SC batches of 8 dwords, depth 2 SCs
  int qv[2][4][2];
  #pragma unroll
  for (int s = 0; s < 2; ++s)
    #pragma unroll
    for (int ch = 0; ch < 4; ++ch) {
      const size_t ro = (size_t)(s * 16 + ch * 4) * NN;
      qv[s][ch][0] = qwl[ro];
      qv[s][ch][1] = qwl[ro + 16];
    }

  // B-frag base: unit = (rbase + g*4 + quad)*64 + mt*16 + ml
  const s16x8* xb = (const s16x8*)xT8;
  const int bbase = (rbase + quad) * MM + ml;
  s16x8 bf[2][4];
  #pragma unroll
  for (int mt = 0; mt < 4; ++mt) bf[0][mt] = xb[bbase + mt * 16];

  f32x4 acc[2][4];
  #pragma unroll
  for (int a = 0; a < 2; ++a)
    #pragma unroll
    for (int b = 0; b < 4; ++b) acc[a][b] = {0.f, 0.f, 0.f, 0.f};

  #pragma unroll
  for (int g = 0; g < NCH; ++g) {
    const int s  = g >> 2;
    const int ch = g & 3;
    const int sl = s & 1;

    if (g + 1 < NCH) {                     // B-frag prefetch, depth 1 chunk
      #pragma unroll
      for (int mt = 0; mt < 4; ++mt)
        bf[(g + 1) & 1][mt] = xb[bbase + (g + 1) * 4 * MM + mt * 16];
    }

    const int v0 = qv[sl][ch][0], v1 = qv[sl][ch][1];
    if (s + 2 < 4) {                       // qw refill, 2 SCs ahead
      const size_t ro = (size_t)((s + 2) * 16 + ch * 4) * NN;
      qv[sl][ch][0] = qwl[ro];
      qv[sl][ch][1] = qwl[ro + 16];
    }

    // exact dequant: qf=(nib|0x4B000000)=2^23+q; d=qf-C (Sterbenz, integer
    // q-z-1); w=s*d; truncating bf16 pack (one v_perm per pair)
    const float sa = s0[s], sb = s1[s], Ca = C0[s], Cb = C1[s];
    i32x4 b0, b1;
    {
      const float w0 = sa * (__int_as_float(((v0      ) & 15) | 0x4B000000) - Ca);
      const float w1 = sa * (__int_as_float(((v0 >>  4) & 15) | 0x4B000000) - Ca);
      const float w2 = sa * (__int_as_float(((v0 >>  8) & 15) | 0x4B000000) - Ca);
      const float w3 = sa * (__int_as_float(((v0 >> 12) & 15) | 0x4B000000) - Ca);
      const float w4 = sa * (__int_as_float(((v0 >> 16) & 15) | 0x4B000000) - Ca);
      const float w5 = sa * (__int_as_float(((v0 >> 20) & 15) | 0x4B000000) - Ca);
      const float w6 = sa * (__int_as_float(((v0 >> 24) & 15) | 0x4B000000) - Ca);
      const float w7 = sa * (__int_as_float(((v0 >> 28) & 15) | 0x4B000000) - Ca);
      b0.x = perm_trunc(w0, w1); b0.y = perm_trunc(w2, w3);
      b0.z = perm_trunc(w4, w5); b0.w = perm_trunc(w6, w7);
    }
    {
      const float w0 = sb * (__int_as_float(((v1      ) & 15) | 0x4B000000) - Cb);
      const float w1 = sb * (__int_as_float(((v1 >>  4) & 15) | 0x4B000000) - Cb);
      const float w2 = sb * (__int_as_float(((v1 >>  8) & 15) | 0x4B000000) - Cb);
      const float w3 = sb * (__int_as_float(((v1 >> 12) & 15) | 0x4B000000) - Cb);
      const float w4 = sb * (__int_as_float(((v1 >> 16) & 15) | 0x4B000000) - Cb);
      const float w5 = sb * (__int_as_float(((v1 >> 20) & 15) | 0x4B000000) - Cb);
      const float w6 = sb * (__int_as_float(((v1 >> 24) & 15) | 0x4B000000) - Cb);
      const float w7 = sb * (__int_as_float(((v1 >> 28) & 15) | 0x4B000000) - Cb);
      b1.x = perm_trunc(w0, w1); b1.y = perm_trunc(w2, w3);
      b1.z = perm_trunc(w4, w5); b1.w = perm_trunc(w6, w7);
    }
    const s16x8 wf0 = __builtin_bit_cast(s16x8, b0);
    const s16x8 wf1 = __builtin_bit_cast(s16x8, b1);

    #pragma unroll
    for (int mt = 0; mt < 4; ++mt) {
      acc[0][mt] = __builtin_amdgcn_mfma_f32_16x16x32_bf16(wf0, bf[g & 1][mt], acc[0][mt], 0, 0, 0);
      acc[1][mt] = __builtin_amdgcn_mfma_f32_16x16x32_bf16(wf1, bf[g & 1][mt], acc[1][mt], 0, 0, 0);
    }
  }

  // ---- epilogue ----
  if (ATOMIC) {
    #pragma unroll
    for (int ns = 0; ns < 2; ++ns)
      #pragma unroll
      for (int mt = 0; mt < 4; ++mt) {
        const int m = mt * 16 + ml;
        const int nb = nw0 + ns * 16 + quad * 4;
        const f32x4 a = acc[ns][mt];
        atomicAdd(&outws[(size_t)m * NN + nb + 0], a.x);
        atomicAdd(&outws[(size_t)m * NN + nb + 1], a.y);
        atomicAdd(&outws[(size_t)m * NN + nb + 2], a.z);
        atomicAdd(&outws[(size_t)m * NN + nb + 3], a.w);
      }
  } else {
    float* wsb = outws + (size_t)blockIdx.x * BLK_FLOATS;
    #pragma unroll
    for (int ns = 0; ns < 2; ++ns)
      #pragma unroll
      for (int mt = 0; mt < 4; ++mt)
        *(f32x4*)(wsb + ((wave * 8 + ns * 4 + mt) * 64 + lane) * 4) = acc[ns][mt];
  }
}

} // namespace

extern "C" void kernel_launch(void* const* d_in, const int* in_sizes, int n_in,
                              void* d_out, int out_size, void* d_ws, size_t ws_size,
                              hipStream_t stream) {
  const float* x      = (const float*)d_in[0];
  const int*   qw     = (const int*)d_in[1];
  const int*   qz     = (const int*)d_in[2];
  const float* scales = (const float*)d_in[3];
  const float* bias   = (const float*)d_in[4];
  float* out = (float*)d_out;

  if (ws_size >= WS_NEED) {
    float* ws   = (float*)d_ws;
    short* xT8  = (short*)(ws + XT8_OFF);
    xt8_kernel<<<2 * MM, 256, 0, stream>>>(x, xT8);
    gptq_gemm_kernel<false><<<NTILES * KSPLIT, 256, 0, stream>>>(qw, qz, scales, xT8, ws);
    reduce_kernel<<<(MM * NN) / 1024, 256, 0, stream>>>(ws, bias, out);
  } else {
    xt8_kernel<<<2 * MM, 256, 0, stream>>>(x, nullptr);
    prep_kernel<<<(MM * NN) / 256, 256, 0, stream>>>(bias, out);
    gptq_gemm_kernel<true><<<NTILES * KSPLIT, 256, 0, stream>>>(qw, qz, scales, nullptr, out);
  }
}